// Round 7
// baseline (429.385 us; speedup 1.0000x reference)
//
#include <hip/hip_runtime.h>
#include <hip/hip_bf16.h>
#include <math.h>

typedef unsigned short u16;
typedef short bf16x8 __attribute__((ext_vector_type(8)));
typedef float f32x4 __attribute__((ext_vector_type(4)));

#define NB 8
#define NN 56          // h == w
#define M2 112         // 2n
#define EMB 192
#define D1 576
#define TOK (NB*NN*NN) // 25088

__device__ __forceinline__ float bf2f(unsigned int u) {
    union { unsigned int i; float f; } v; v.i = u << 16; return v.f;
}
__device__ __forceinline__ u16 f2bf(float f) {
    union { float f; unsigned int i; } v; v.f = f;
    unsigned int x = v.i;
    return (u16)((x + 0x7fffu + ((x >> 16) & 1u)) >> 16);
}
__device__ __forceinline__ float silu(float x) {
    return x / (1.0f + __expf(-x));
}
__device__ __forceinline__ void async16(void* lds, const void* g) {
    __builtin_amdgcn_global_load_lds(
        (const __attribute__((address_space(1))) void*)g,
        (__attribute__((address_space(3))) void*)lds, 16, 0, 0);
}

// ---------------- K0: fp32 -> bf16 convert (x, pw, qw, vw, ow) ------------
#define XCH (TOK*EMB/4)
#define WCH (D1*EMB/4)
__global__ __launch_bounds__(256) void convert_kernel(
    const float* __restrict__ x,
    const float* __restrict__ pw, const float* __restrict__ qw,
    const float* __restrict__ vw, const float* __restrict__ ow,
    u16* __restrict__ xb, u16* __restrict__ wb, u16* __restrict__ owb)
{
    int tid = blockIdx.x * 256 + threadIdx.x;
    const float* src; u16* dst; int off;
    if (tid < XCH) { src = x; dst = xb; off = tid; }
    else {
        int r = tid - XCH;
        int seg = r / WCH; off = r % WCH;
        if (seg == 0)      { src = pw; dst = wb; }
        else if (seg == 1) { src = qw; dst = wb + D1*EMB; }
        else if (seg == 2) { src = vw; dst = wb + 2*D1*EMB; }
        else if (seg == 3) { src = ow; dst = owb; }
        else return;
    }
    float4 f = *(const float4*)(src + off * 4);
    ushort4 o;
    o.x = f2bf(f.x); o.y = f2bf(f.y); o.z = f2bf(f.z); o.w = f2bf(f.w);
    *(ushort4*)(dst + off * 4) = o;
}

// ---------------- K1: RPE MLP + decay -> A1, A2 (fp32, 112 x 576 each) ----
__global__ __launch_bounds__(576) void rpe_kernel(
    const float* __restrict__ slope,
    const float* w0a, const float* b0a, const float* wsa, const float* bsa,
    const float* woa, const float* boa,
    const float* w0b, const float* b0b, const float* wsb, const float* bsb,
    const float* wob, const float* bob,
    float* __restrict__ A1, float* __restrict__ A2)
{
    int wq  = blockIdx.x / M2;
    int row = blockIdx.x % M2;
    const float* w0 = wq ? w0b : w0a;  const float* b0 = wq ? b0b : b0a;
    const float* ws = wq ? wsb : wsa;  const float* bs = wq ? bsb : bsa;
    const float* wo = wq ? wob : woa;  const float* bo = wq ? bob : boa;
    float* A = wq ? A2 : A1;

    float tval = (row == 0 || row == 56) ? 0.0f
               : (row < 56 ? (float)row : -(float)(row - 56));
    int kexp = (row == 0 || row == 56) ? 0 : (row < 56 ? row : 112 - row);

    __shared__ float h[32], g[32];
    int t = threadIdx.x;
    if (t < 32) h[t] = tval * w0[t] + b0[t];
    __syncthreads();
    for (int L = 0; L < 3; L++) {
        if (t < 32) g[t] = fmaxf(h[t], 0.0f);
        __syncthreads();
        float hn = 0.0f;
        if (t < 32) {
            hn = bs[L * 32 + t];
            for (int k = 0; k < 32; k++)
                hn = fmaf(g[k], ws[(L * 32 + t) * 32 + k], hn);
        }
        __syncthreads();
        if (t < 32) h[t] = hn;
        __syncthreads();
    }
    if (t < 32) g[t] = fmaxf(h[t], 0.0f);
    __syncthreads();

    float o = bo[t];
    for (int k = 0; k < 32; k++)
        o = fmaf(g[k], wo[t * 32 + k], o);

    float sl = slope[t];
    sl = 0.95f + 0.05f * fminf(fmaxf(sl, 0.0f), 1.0f);
    float dec = powf(sl, (float)kexp);
    A[row * D1 + t] = o * dec;
}

// ---------------- K1b: build Toeplitz matrices T[d][i64][j64] bf16 --------
// T[i][j] = a_d[i-j] for i,j < 56, else 0.  Plain chunk layout; the tno
// kernels apply the XOR swizzle on the global chunk index when staging.
__global__ __launch_bounds__(256) void tbuild_kernel(
    const float* __restrict__ A1, const float* __restrict__ A2,
    u16* __restrict__ T1t, u16* __restrict__ T2t)
{
    int d = blockIdx.x;
    const float* src = blockIdx.y ? A2 : A1;
    u16* dst = blockIdx.y ? T2t : T1t;
    __shared__ float win[111];
    int t = threadIdx.x;
    if (t < 111) {
        int lag = t - 55;
        int rowi = lag + (lag < 0 ? 112 : 0);
        win[t] = src[rowi * D1 + d];
    }
    __syncthreads();
    int i = t >> 2, jq = (t & 3) * 16;
    u16 vals[16];
    #pragma unroll
    for (int jj = 0; jj < 16; jj++) {
        int j = jq + jj;
        float v = (i < 56 && j < 56) ? win[i - j + 55] : 0.0f;
        vals[jj] = f2bf(v);
    }
    u16* out = dst + ((size_t)d * 64 + i) * 64 + jq;
    *(uint4*)(out)     = *(uint4*)&vals[0];
    *(uint4*)(out + 8) = *(uint4*)&vals[8];
}

// ---------------- K2: MFMA proj --------------------------------------------
__global__ __launch_bounds__(256) void proj_kernel(
    const u16* __restrict__ xb, const u16* __restrict__ wb,
    const float* __restrict__ pb, const float* __restrict__ qb,
    const float* __restrict__ vb,
    u16* __restrict__ P, u16* __restrict__ QV)
{
    __shared__ u16 lds[20480];          // 40 KB: As 8192 u16, Bs 12288 u16
    u16* As = lds;
    u16* Bs = lds + 8192;
    int m0 = blockIdx.x * 128, n0 = blockIdx.y * 64;
    int t = threadIdx.x;
    int l = t & 63, wave = t >> 6;
    int wm = wave >> 1, wn = wave & 1;
    int col16 = l & 15, q = l >> 4;

    f32x4 accp[4][2], accq[4][2], accv[4][2];
    #pragma unroll
    for (int i = 0; i < 4; i++)
        #pragma unroll
        for (int j = 0; j < 2; j++) {
            accp[i][j] = (f32x4){0,0,0,0};
            accq[i][j] = (f32x4){0,0,0,0};
            accv[i][j] = (f32x4){0,0,0,0};
        }

    for (int k0 = 0; k0 < EMB; k0 += 64) {
        #pragma unroll
        for (int ii = 0; ii < 4; ii++) {
            int slot = (ii * 4 + wave) * 64 + l;
            int r = slot >> 3, s = slot & 7;
            int g = s ^ (r & 7);
            async16(&As[slot * 8], xb + (m0 + r) * EMB + k0 + g * 8);
        }
        #pragma unroll
        for (int ii = 0; ii < 6; ii++) {
            int slot = (ii * 4 + wave) * 64 + l;
            int mat = slot >> 9, cc = slot & 511;
            int r = cc >> 3, s = cc & 7;
            int g = s ^ (r & 7);
            async16(&Bs[slot * 8],
                    wb + mat * (D1 * EMB) + (n0 + r) * EMB + k0 + g * 8);
        }
        __syncthreads();

        #pragma unroll
        for (int kk = 0; kk < 2; kk++) {
            bf16x8 af[4];
            #pragma unroll
            for (int mt = 0; mt < 4; mt++) {
                int row = wm * 64 + mt * 16 + col16;
                int sw = (q + 4 * kk) ^ (col16 & 7);
                af[mt] = *(const bf16x8*)&As[row * 64 + sw * 8];
            }
            bf16x8 bfr[3][2];
            #pragma unroll
            for (int mat = 0; mat < 3; mat++)
                #pragma unroll
                for (int nt = 0; nt < 2; nt++) {
                    int row = wn * 32 + nt * 16 + col16;
                    int sw = (q + 4 * kk) ^ (col16 & 7);
                    bfr[mat][nt] = *(const bf16x8*)&Bs[mat * 4096 + row * 64 + sw * 8];
                }
            #pragma unroll
            for (int mt = 0; mt < 4; mt++)
                #pragma unroll
                for (int nt = 0; nt < 2; nt++) {
                    accp[mt][nt] = __builtin_amdgcn_mfma_f32_16x16x32_bf16(
                        af[mt], bfr[0][nt], accp[mt][nt], 0, 0, 0);
                    accq[mt][nt] = __builtin_amdgcn_mfma_f32_16x16x32_bf16(
                        af[mt], bfr[1][nt], accq[mt][nt], 0, 0, 0);
                    accv[mt][nt] = __builtin_amdgcn_mfma_f32_16x16x32_bf16(
                        af[mt], bfr[2][nt], accv[mt][nt], 0, 0, 0);
                }
        }
        __syncthreads();
    }

    u16* scr = lds + wave * 2560;
    float pbv[2], qbv[2], vbv[2];
    #pragma unroll
    for (int nt = 0; nt < 2; nt++) {
        int n = n0 + wn * 32 + nt * 16 + col16;
        pbv[nt] = pb[n]; qbv[nt] = qb[n]; vbv[nt] = vb[n];
    }
    #pragma unroll
    for (int mt = 0; mt < 4; mt++)
        #pragma unroll
        for (int nt = 0; nt < 2; nt++)
            #pragma unroll
            for (int r = 0; r < 4; r++)
                scr[(mt * 16 + q * 4 + r) * 40 + nt * 16 + col16] =
                    f2bf(silu(accp[mt][nt][r] + pbv[nt]));
    #pragma unroll
    for (int k = 0; k < 4; k++) {
        int row = k * 16 + (l >> 2), cs = (l & 3) * 8;
        uint4 v = *(const uint4*)&scr[row * 40 + cs];
        *(uint4*)&P[(m0 + wm * 64 + row) * D1 + n0 + wn * 32 + cs] = v;
    }
    #pragma unroll
    for (int mt = 0; mt < 4; mt++)
        #pragma unroll
        for (int nt = 0; nt < 2; nt++)
            #pragma unroll
            for (int r = 0; r < 4; r++)
                scr[(mt * 16 + q * 4 + r) * 40 + nt * 16 + col16] =
                    f2bf(silu(accq[mt][nt][r] + qbv[nt]) *
                         silu(accv[mt][nt][r] + vbv[nt]));
    #pragma unroll
    for (int k = 0; k < 4; k++) {
        int row = k * 16 + (l >> 2), cs = (l & 3) * 8;
        uint4 v = *(const uint4*)&scr[row * 40 + cs];
        *(uint4*)&QV[(m0 + wm * 64 + row) * D1 + n0 + wn * 32 + cs] = v;
    }
}

// ---------------- K3: MFMA Toeplitz along W --------------------------------
// Block = (4 d's, 16 rows of (b,h)); wave = one d.
// A-op = T_d[m=i][k=j] (64x64, swizzled chunks), B-op = Q[k=j][n=row].
// C[m=i][n=row] -> LDS repack [row][i][d4] -> b64 global stores.
__global__ __launch_bounds__(256) void tno_w_mfma(
    const u16* __restrict__ QV, const u16* __restrict__ T1t,
    u16* __restrict__ O)
{
    __shared__ u16 lds[20992];       // Ts 16384 + Qs 4608 u16 = 42 KB
    u16* Ts = lds;                    // [d4][i64][8 chunks swizzled]
    u16* Qs = lds + 16384;            // [d4][row16][j72]
    u16* epi = lds;                   // alias after compute
    int t = threadIdx.x;
    int d0 = blockIdx.x * 4;
    int r0 = blockIdx.y * 16;

    #pragma unroll
    for (int k = 0; k < 8; k++) {
        int slot = t + k * 256;
        int dd = slot >> 9, rem = slot & 511;
        int i = rem >> 3, s = rem & 7;
        int g = s ^ (i & 7);
        async16(&Ts[slot * 8], T1t + (((size_t)(d0 + dd) * 64 + i) * 64 + g * 8));
    }
    for (int idx = t; idx < 896; idx += 256) {
        int row = idx / 56, j = idx % 56;
        ushort4 v = *(const ushort4*)(QV + (size_t)((r0 + row) * 56 + j) * D1 + d0);
        Qs[0 * 1152 + row * 72 + j] = v.x;
        Qs[1 * 1152 + row * 72 + j] = v.y;
        Qs[2 * 1152 + row * 72 + j] = v.z;
        Qs[3 * 1152 + row * 72 + j] = v.w;
    }
    for (int z = t; z < 512; z += 256) {
        int dd = z >> 7, rem = z & 127;
        int row = rem >> 3, j = 56 + (rem & 7);
        Qs[dd * 1152 + row * 72 + j] = 0;
    }
    __syncthreads();

    int l = t & 63, dd = t >> 6;
    int col16 = l & 15, q = l >> 4;
    const u16* Tw = &Ts[dd * 4096];
    const u16* Qw = &Qs[dd * 1152];
    f32x4 acc[4];
    #pragma unroll
    for (int i = 0; i < 4; i++) acc[i] = (f32x4){0,0,0,0};
    #pragma unroll
    for (int kk = 0; kk < 2; kk++) {
        bf16x8 bq = *(const bf16x8*)&Qw[col16 * 72 + kk * 32 + q * 8];
        #pragma unroll
        for (int mt = 0; mt < 4; mt++) {
            int i = mt * 16 + col16;
            bf16x8 at = *(const bf16x8*)&Tw[i * 64 + ((4 * kk + q) ^ (col16 & 7)) * 8];
            acc[mt] = __builtin_amdgcn_mfma_f32_16x16x32_bf16(at, bq, acc[mt], 0, 0, 0);
        }
    }

    __syncthreads();
    #pragma unroll
    for (int mt = 0; mt < 4; mt++)
        #pragma unroll
        for (int r = 0; r < 4; r++) {
            int i = mt * 16 + q * 4 + r;
            if (i < 56)
                epi[(col16 * 56 + i) * 4 + dd] = f2bf(acc[mt][r]);
        }
    __syncthreads();
    for (int idx = t; idx < 896; idx += 256) {
        int row = idx / 56, i = idx % 56;
        ushort4 v = *(const ushort4*)&epi[(row * 56 + i) * 4];
        *(ushort4*)(O + (size_t)((r0 + row) * 56 + i) * D1 + d0) = v;
    }
}

// ---------------- K4: MFMA Toeplitz along H + fuse U = P.*(o1+o2) ----------
// rows = (b,w) pairs; contraction over h; epilogue fuses O read + P mul.
__global__ __launch_bounds__(256) void tno_h_mfma(
    const u16* __restrict__ QV, const u16* __restrict__ T2t,
    const u16* __restrict__ O, u16* __restrict__ PU)
{
    __shared__ u16 lds[20992];
    u16* Ts = lds;
    u16* Qs = lds + 16384;
    u16* epi = lds;
    int t = threadIdx.x;
    int d0 = blockIdx.x * 4;
    int r0 = blockIdx.y * 16;

    #pragma unroll
    for (int k = 0; k < 8; k++) {
        int slot = t + k * 256;
        int dd = slot >> 9, rem = slot & 511;
        int i = rem >> 3, s = rem & 7;
        int g = s ^ (i & 7);
        async16(&Ts[slot * 8], T2t + (((size_t)(d0 + dd) * 64 + i) * 64 + g * 8));
    }
    for (int idx = t; idx < 896; idx += 256) {
        int row = idx / 56, j = idx % 56;
        int rr = r0 + row;
        int b = rr / 56, w = rr % 56;
        ushort4 v = *(const ushort4*)(QV + (size_t)((b * 56 + j) * 56 + w) * D1 + d0);
        Qs[0 * 1152 + row * 72 + j] = v.x;
        Qs[1 * 1152 + row * 72 + j] = v.y;
        Qs[2 * 1152 + row * 72 + j] = v.z;
        Qs[3 * 1152 + row * 72 + j] = v.w;
    }
    for (int z = t; z < 512; z += 256) {
        int dd = z >> 7, rem = z & 127;
        int row = rem >> 3, j = 56 + (rem & 7);
        Qs[dd * 1152 + row * 72 + j] = 0;
    }
    __syncthreads();

    int l = t & 63, dd = t >> 6;
    int col16 = l & 15, q = l >> 4;
    const u16* Tw = &Ts[dd * 4096];
    const u16* Qw = &Qs[dd * 1152];
    f32x4 acc[4];
    #pragma unroll
    for (int i = 0; i < 4; i++) acc[i] = (f32x4){0,0,0,0};
    #pragma unroll
    for (int kk = 0; kk < 2; kk++) {
        bf16x8 bq = *(const bf16x8*)&Qw[col16 * 72 + kk * 32 + q * 8];
        #pragma unroll
        for (int mt = 0; mt < 4; mt++) {
            int i = mt * 16 + col16;
            bf16x8 at = *(const bf16x8*)&Tw[i * 64 + ((4 * kk + q) ^ (col16 & 7)) * 8];
            acc[mt] = __builtin_amdgcn_mfma_f32_16x16x32_bf16(at, bq, acc[mt], 0, 0, 0);
        }
    }

    __syncthreads();
    #pragma unroll
    for (int mt = 0; mt < 4; mt++)
        #pragma unroll
        for (int r = 0; r < 4; r++) {
            int i = mt * 16 + q * 4 + r;
            if (i < 56)
                epi[(col16 * 56 + i) * 4 + dd] = f2bf(acc[mt][r]);
        }
    __syncthreads();
    for (int idx = t; idx < 896; idx += 256) {
        int row = idx / 56, i = idx % 56;
        int rr = r0 + row;
        int b = rr / 56, w = rr % 56;
        size_t gidx = (size_t)((b * 56 + i) * 56 + w) * D1 + d0;
        ushort4 ov = *(const ushort4*)(O + gidx);
        ushort4 pv = *(const ushort4*)(PU + gidx);
        ushort4 ev = *(const ushort4*)&epi[(row * 56 + i) * 4];
        ushort4 uv;
        uv.x = f2bf(bf2f(pv.x) * (bf2f(ov.x) + bf2f(ev.x)));
        uv.y = f2bf(bf2f(pv.y) * (bf2f(ov.y) + bf2f(ev.y)));
        uv.z = f2bf(bf2f(pv.z) * (bf2f(ov.z) + bf2f(ev.z)));
        uv.w = f2bf(bf2f(pv.w) * (bf2f(ov.w) + bf2f(ev.w)));
        *(ushort4*)(PU + gidx) = uv;
    }
}

// ---------------- K5: MFMA outproj: out = U @ ow^T + ob -------------------
__global__ __launch_bounds__(256) void outproj_kernel(
    const u16* __restrict__ U, const u16* __restrict__ owb,
    const float* __restrict__ ob, float* __restrict__ out)
{
    __shared__ char ldsraw[36864];
    u16* As = (u16*)ldsraw;
    u16* Bs = (u16*)(ldsraw + 16384);
    int m0 = blockIdx.x * 128, n0 = blockIdx.y * 64;
    int t = threadIdx.x;
    int l = t & 63, wave = t >> 6;
    int wm = wave >> 1, wn = wave & 1;
    int col16 = l & 15, q = l >> 4;

    f32x4 acc[4][2];
    #pragma unroll
    for (int i = 0; i < 4; i++)
        #pragma unroll
        for (int j = 0; j < 2; j++) acc[i][j] = (f32x4){0,0,0,0};

    for (int k0 = 0; k0 < D1; k0 += 64) {
        #pragma unroll
        for (int ii = 0; ii < 4; ii++) {
            int slot = (ii * 4 + wave) * 64 + l;
            int r = slot >> 3, s = slot & 7;
            int g = s ^ (r & 7);
            async16(&As[slot * 8], U + (m0 + r) * D1 + k0 + g * 8);
        }
        #pragma unroll
        for (int ii = 0; ii < 2; ii++) {
            int slot = (ii * 4 + wave) * 64 + l;
            int r = slot >> 3, s = slot & 7;
            int g = s ^ (r & 7);
            async16(&Bs[slot * 8], owb + (n0 + r) * D1 + k0 + g * 8);
        }
        __syncthreads();

        #pragma unroll
        for (int kk = 0; kk < 2; kk++) {
            int sw = (q + 4 * kk) ^ (col16 & 7);
            bf16x8 af[4];
            #pragma unroll
            for (int mt = 0; mt < 4; mt++)
                af[mt] = *(const bf16x8*)&As[(wm * 64 + mt * 16 + col16) * 64 + sw * 8];
            bf16x8 bfr[2];
            #pragma unroll
            for (int nt = 0; nt < 2; nt++)
                bfr[nt] = *(const bf16x8*)&Bs[(wn * 32 + nt * 16 + col16) * 64 + sw * 8];
            #pragma unroll
            for (int mt = 0; mt < 4; mt++)
                #pragma unroll
                for (int nt = 0; nt < 2; nt++)
                    acc[mt][nt] = __builtin_amdgcn_mfma_f32_16x16x32_bf16(
                        af[mt], bfr[nt], acc[mt][nt], 0, 0, 0);
        }
        __syncthreads();
    }

    float* scr = (float*)ldsraw + wave * 2304;
    float obv[2];
    #pragma unroll
    for (int nt = 0; nt < 2; nt++)
        obv[nt] = ob[n0 + wn * 32 + nt * 16 + col16];
    #pragma unroll
    for (int mt = 0; mt < 4; mt++)
        #pragma unroll
        for (int nt = 0; nt < 2; nt++)
            #pragma unroll
            for (int r = 0; r < 4; r++)
                scr[(mt * 16 + q * 4 + r) * 36 + nt * 16 + col16] =
                    acc[mt][nt][r] + obv[nt];
    #pragma unroll
    for (int k = 0; k < 8; k++) {
        int row = k * 8 + (l >> 3), cs = (l & 7) * 4;
        f32x4 v = *(const f32x4*)&scr[row * 36 + cs];
        *(f32x4*)&out[(m0 + wm * 64 + row) * EMB + n0 + wn * 32 + cs] = v;
    }
}

extern "C" void kernel_launch(void* const* d_in, const int* in_sizes, int n_in,
                              void* d_out, int out_size, void* d_ws, size_t ws_size,
                              hipStream_t stream)
{
    (void)in_sizes; (void)n_in; (void)out_size; (void)ws_size;
    const float* x     = (const float*)d_in[0];
    const float* p_w   = (const float*)d_in[1];
    const float* p_b   = (const float*)d_in[2];
    const float* q_w   = (const float*)d_in[3];
    const float* q_b   = (const float*)d_in[4];
    const float* v_w   = (const float*)d_in[5];
    const float* v_b   = (const float*)d_in[6];
    const float* o_w   = (const float*)d_in[7];
    const float* o_b   = (const float*)d_in[8];
    const float* slope = (const float*)d_in[9];
    const float* t1_w0 = (const float*)d_in[10];
    const float* t1_b0 = (const float*)d_in[11];
    const float* t1_ws = (const float*)d_in[12];
    const float* t1_bs = (const float*)d_in[13];
    const float* t1_wo = (const float*)d_in[14];
    const float* t1_bo = (const float*)d_in[15];
    const float* t2_w0 = (const float*)d_in[16];
    const float* t2_b0 = (const float*)d_in[17];
    const float* t2_ws = (const float*)d_in[18];
    const float* t2_bs = (const float*)d_in[19];
    const float* t2_wo = (const float*)d_in[20];
    const float* t2_bo = (const float*)d_in[21];

    char* ws = (char*)d_ws;
    float* A1 = (float*)ws;                      // 258048 B
    float* A2 = (float*)(ws + 258048);           // 258048 B
    u16*   PU = (u16*)(ws + 516096);             // 28901376 B (P, later U)
    u16*   QV = (u16*)(ws + 29417472);           // 28901376 B
    u16*   O  = (u16*)(ws + 58318848);           // 28901376 B (bf16)
    u16*   xb = (u16*)(ws + 87220224);           // 9633792 B
    u16*   wb = (u16*)(ws + 96854016);           // 663552 B
    u16*   owb= (u16*)(ws + 97517568);           // 221184 B
    u16*   T1t= (u16*)(ws + 97738752);           // 4718592 B
    u16*   T2t= (u16*)(ws + 102457344);          // 4718592 B

    convert_kernel<<<(XCH + 4*WCH + 255) / 256, 256, 0, stream>>>(
        x, p_w, q_w, v_w, o_w, xb, wb, owb);
    rpe_kernel<<<224, 576, 0, stream>>>(slope,
        t1_w0, t1_b0, t1_ws, t1_bs, t1_wo, t1_bo,
        t2_w0, t2_b0, t2_ws, t2_bs, t2_wo, t2_bo, A1, A2);
    tbuild_kernel<<<dim3(576, 2), 256, 0, stream>>>(A1, A2, T1t, T2t);
    proj_kernel<<<dim3(TOK / 128, D1 / 64), 256, 0, stream>>>(
        xb, wb, p_b, q_b, v_b, PU, QV);
    tno_w_mfma<<<dim3(D1 / 4, 28), 256, 0, stream>>>(QV, T1t, O);
    tno_h_mfma<<<dim3(D1 / 4, 28), 256, 0, stream>>>(QV, T2t, O, PU);
    outproj_kernel<<<dim3(TOK / 128, EMB / 64), 256, 0, stream>>>(
        PU, owb, o_b, (float*)d_out);
}

// Round 8
// 238.625 us; speedup vs baseline: 1.7994x; 1.7994x over previous
//
#include <hip/hip_runtime.h>
#include <hip/hip_bf16.h>
#include <math.h>

typedef unsigned short u16;
typedef short bf16x8 __attribute__((ext_vector_type(8)));
typedef float f32x4 __attribute__((ext_vector_type(4)));

#define NB 8
#define NN 56          // h == w
#define M2 112         // 2n
#define EMB 192
#define D1 576
#define TOK (NB*NN*NN) // 25088

__device__ __forceinline__ float bf2f(unsigned int u) {
    union { unsigned int i; float f; } v; v.i = u << 16; return v.f;
}
__device__ __forceinline__ u16 f2bf(float f) {
    union { float f; unsigned int i; } v; v.f = f;
    unsigned int x = v.i;
    return (u16)((x + 0x7fffu + ((x >> 16) & 1u)) >> 16);
}
__device__ __forceinline__ float silu(float x) {
    return x / (1.0f + __expf(-x));
}
__device__ __forceinline__ void async16(void* lds, const void* g) {
    __builtin_amdgcn_global_load_lds(
        (const __attribute__((address_space(1))) void*)g,
        (__attribute__((address_space(3))) void*)lds, 16, 0, 0);
}

// ---------------- K0: fp32 -> bf16 convert (x, pw, qw, vw, ow) ------------
#define XCH (TOK*EMB/4)
#define WCH (D1*EMB/4)
__global__ __launch_bounds__(256) void convert_kernel(
    const float* __restrict__ x,
    const float* __restrict__ pw, const float* __restrict__ qw,
    const float* __restrict__ vw, const float* __restrict__ ow,
    u16* __restrict__ xb, u16* __restrict__ wb, u16* __restrict__ owb)
{
    int tid = blockIdx.x * 256 + threadIdx.x;
    const float* src; u16* dst; int off;
    if (tid < XCH) { src = x; dst = xb; off = tid; }
    else {
        int r = tid - XCH;
        int seg = r / WCH; off = r % WCH;
        if (seg == 0)      { src = pw; dst = wb; }
        else if (seg == 1) { src = qw; dst = wb + D1*EMB; }
        else if (seg == 2) { src = vw; dst = wb + 2*D1*EMB; }
        else if (seg == 3) { src = ow; dst = owb; }
        else return;
    }
    float4 f = *(const float4*)(src + off * 4);
    ushort4 o;
    o.x = f2bf(f.x); o.y = f2bf(f.y); o.z = f2bf(f.z); o.w = f2bf(f.w);
    *(ushort4*)(dst + off * 4) = o;
}

// ---------------- K1: RPE MLP + decay -> A1, A2 (fp32, 112 x 576 each) ----
__global__ __launch_bounds__(576) void rpe_kernel(
    const float* __restrict__ slope,
    const float* w0a, const float* b0a, const float* wsa, const float* bsa,
    const float* woa, const float* boa,
    const float* w0b, const float* b0b, const float* wsb, const float* bsb,
    const float* wob, const float* bob,
    float* __restrict__ A1, float* __restrict__ A2)
{
    int wq  = blockIdx.x / M2;
    int row = blockIdx.x % M2;
    const float* w0 = wq ? w0b : w0a;  const float* b0 = wq ? b0b : b0a;
    const float* ws = wq ? wsb : wsa;  const float* bs = wq ? bsb : bsa;
    const float* wo = wq ? wob : woa;  const float* bo = wq ? bob : boa;
    float* A = wq ? A2 : A1;

    float tval = (row == 0 || row == 56) ? 0.0f
               : (row < 56 ? (float)row : -(float)(row - 56));
    int kexp = (row == 0 || row == 56) ? 0 : (row < 56 ? row : 112 - row);

    __shared__ float h[32], g[32];
    int t = threadIdx.x;
    if (t < 32) h[t] = tval * w0[t] + b0[t];
    __syncthreads();
    for (int L = 0; L < 3; L++) {
        if (t < 32) g[t] = fmaxf(h[t], 0.0f);
        __syncthreads();
        float hn = 0.0f;
        if (t < 32) {
            hn = bs[L * 32 + t];
            for (int k = 0; k < 32; k++)
                hn = fmaf(g[k], ws[(L * 32 + t) * 32 + k], hn);
        }
        __syncthreads();
        if (t < 32) h[t] = hn;
        __syncthreads();
    }
    if (t < 32) g[t] = fmaxf(h[t], 0.0f);
    __syncthreads();

    float o = bo[t];
    for (int k = 0; k < 32; k++)
        o = fmaf(g[k], wo[t * 32 + k], o);

    float sl = slope[t];
    sl = 0.95f + 0.05f * fminf(fmaxf(sl, 0.0f), 1.0f);
    float dec = powf(sl, (float)kexp);
    A[row * D1 + t] = o * dec;
}

// ---------------- K2: MFMA proj --------------------------------------------
__global__ __launch_bounds__(256) void proj_kernel(
    const u16* __restrict__ xb, const u16* __restrict__ wb,
    const float* __restrict__ pb, const float* __restrict__ qb,
    const float* __restrict__ vb,
    u16* __restrict__ P, u16* __restrict__ QV)
{
    __shared__ u16 lds[20480];          // 40 KB: As 8192 u16, Bs 12288 u16
    u16* As = lds;
    u16* Bs = lds + 8192;
    int m0 = blockIdx.x * 128, n0 = blockIdx.y * 64;
    int t = threadIdx.x;
    int l = t & 63, wave = t >> 6;
    int wm = wave >> 1, wn = wave & 1;
    int col16 = l & 15, q = l >> 4;

    f32x4 accp[4][2], accq[4][2], accv[4][2];
    #pragma unroll
    for (int i = 0; i < 4; i++)
        #pragma unroll
        for (int j = 0; j < 2; j++) {
            accp[i][j] = (f32x4){0,0,0,0};
            accq[i][j] = (f32x4){0,0,0,0};
            accv[i][j] = (f32x4){0,0,0,0};
        }

    for (int k0 = 0; k0 < EMB; k0 += 64) {
        #pragma unroll
        for (int ii = 0; ii < 4; ii++) {
            int slot = (ii * 4 + wave) * 64 + l;
            int r = slot >> 3, s = slot & 7;
            int g = s ^ (r & 7);
            async16(&As[slot * 8], xb + (m0 + r) * EMB + k0 + g * 8);
        }
        #pragma unroll
        for (int ii = 0; ii < 6; ii++) {
            int slot = (ii * 4 + wave) * 64 + l;
            int mat = slot >> 9, cc = slot & 511;
            int r = cc >> 3, s = cc & 7;
            int g = s ^ (r & 7);
            async16(&Bs[slot * 8],
                    wb + mat * (D1 * EMB) + (n0 + r) * EMB + k0 + g * 8);
        }
        __syncthreads();

        #pragma unroll
        for (int kk = 0; kk < 2; kk++) {
            bf16x8 af[4];
            #pragma unroll
            for (int mt = 0; mt < 4; mt++) {
                int row = wm * 64 + mt * 16 + col16;
                int sw = (q + 4 * kk) ^ (col16 & 7);
                af[mt] = *(const bf16x8*)&As[row * 64 + sw * 8];
            }
            bf16x8 bfr[3][2];
            #pragma unroll
            for (int mat = 0; mat < 3; mat++)
                #pragma unroll
                for (int nt = 0; nt < 2; nt++) {
                    int row = wn * 32 + nt * 16 + col16;
                    int sw = (q + 4 * kk) ^ (col16 & 7);
                    bfr[mat][nt] = *(const bf16x8*)&Bs[mat * 4096 + row * 64 + sw * 8];
                }
            #pragma unroll
            for (int mt = 0; mt < 4; mt++)
                #pragma unroll
                for (int nt = 0; nt < 2; nt++) {
                    accp[mt][nt] = __builtin_amdgcn_mfma_f32_16x16x32_bf16(
                        af[mt], bfr[0][nt], accp[mt][nt], 0, 0, 0);
                    accq[mt][nt] = __builtin_amdgcn_mfma_f32_16x16x32_bf16(
                        af[mt], bfr[1][nt], accq[mt][nt], 0, 0, 0);
                    accv[mt][nt] = __builtin_amdgcn_mfma_f32_16x16x32_bf16(
                        af[mt], bfr[2][nt], accv[mt][nt], 0, 0, 0);
                }
        }
        __syncthreads();
    }

    u16* scr = lds + wave * 2560;
    float pbv[2], qbv[2], vbv[2];
    #pragma unroll
    for (int nt = 0; nt < 2; nt++) {
        int n = n0 + wn * 32 + nt * 16 + col16;
        pbv[nt] = pb[n]; qbv[nt] = qb[n]; vbv[nt] = vb[n];
    }
    #pragma unroll
    for (int mt = 0; mt < 4; mt++)
        #pragma unroll
        for (int nt = 0; nt < 2; nt++)
            #pragma unroll
            for (int r = 0; r < 4; r++)
                scr[(mt * 16 + q * 4 + r) * 40 + nt * 16 + col16] =
                    f2bf(silu(accp[mt][nt][r] + pbv[nt]));
    #pragma unroll
    for (int k = 0; k < 4; k++) {
        int row = k * 16 + (l >> 2), cs = (l & 3) * 8;
        uint4 v = *(const uint4*)&scr[row * 40 + cs];
        *(uint4*)&P[(m0 + wm * 64 + row) * D1 + n0 + wn * 32 + cs] = v;
    }
    #pragma unroll
    for (int mt = 0; mt < 4; mt++)
        #pragma unroll
        for (int nt = 0; nt < 2; nt++)
            #pragma unroll
            for (int r = 0; r < 4; r++)
                scr[(mt * 16 + q * 4 + r) * 40 + nt * 16 + col16] =
                    f2bf(silu(accq[mt][nt][r] + qbv[nt]) *
                         silu(accv[mt][nt][r] + vbv[nt]));
    #pragma unroll
    for (int k = 0; k < 4; k++) {
        int row = k * 16 + (l >> 2), cs = (l & 3) * 8;
        uint4 v = *(const uint4*)&scr[row * 40 + cs];
        *(uint4*)&QV[(m0 + wm * 64 + row) * D1 + n0 + wn * 32 + cs] = v;
    }
}

// ---------------- tno kernels: 4 rows/block, d-tile 32, 8 ig x 8 i ---------
// Thread (d = t&31, ig = t>>5), i0 = 8*ig (ig=7 discarded).
// A-window staged with per-thread b128 writes, stride 124 (conflict-free).
// qs[r][d][j] stride 60: b64 pair-writes (2-way = free), b128 reads.
// Per jg: 7 b128 reads feed 128 FMAs (0.55 LDS-cyc/FMA vs 0.78 at 2 rows).
#define TNO_STAGE4(QLOAD)                                                    \
    __shared__ float qs[4 * 32 * 60];                                        \
    __shared__ float asb[32 * 124];                                          \
    int t = threadIdx.x;                                                     \
    {                                                                        \
        int d = t & 31, sub = t >> 5;                                        \
        int r = sub >> 1;                                                    \
        _Pragma("unroll")                                                    \
        for (int s = 0; s < 14; s++) {                                       \
            int j = ((sub & 1) * 14 + s) * 2;                                \
            float q0, q1;                                                    \
            { int jj = j;     q0 = bf2f(QLOAD); }                            \
            { int jj = j + 1; q1 = bf2f(QLOAD); }                            \
            *(float2*)&qs[r * 1920 + d * 60 + j] = make_float2(q0, q1);      \
        }                                                                    \
        _Pragma("unroll")                                                    \
        for (int it = 0; it < 4; it++) {                                     \
            int pg = sub + 8 * it;           /* 0..31 */                     \
            if (pg < 31) {                                                   \
                f32x4 v;                                                     \
                _Pragma("unroll")                                            \
                for (int k = 0; k < 4; k++) {                                \
                    int p = pg * 4 + k;                                      \
                    float a = 0.0f;                                          \
                    if (p <= 110) {                                          \
                        int lg = p - 55;                                     \
                        int rowi = lg + (lg < 0 ? 112 : 0);                  \
                        a = Aco[rowi * D1 + d0 + d];                         \
                    }                                                        \
                    v[k] = a;                                                \
                }                                                            \
                *(f32x4*)&asb[d * 124 + pg * 4] = v;                         \
            }                                                                \
        }                                                                    \
    }                                                                        \
    __syncthreads();                                                         \
    int d = t & 31, ig = t >> 5;                                             \
    int i0 = ig * 8;                                                         \
    const float* aw = &asb[d * 124];                                         \
    float acc[4][8] = {};                                                    \
    _Pragma("unroll")                                                        \
    for (int jg = 0; jg < 14; jg++) {                                        \
        f32x4 q4[4];                                                         \
        _Pragma("unroll")                                                    \
        for (int r = 0; r < 4; r++)                                          \
            q4[r] = *(const f32x4*)&qs[r * 1920 + d * 60 + jg * 4];          \
        int base = i0 + 52 - 4 * jg;                                         \
        f32x4 a0 = *(const f32x4*)&aw[base];                                 \
        f32x4 a1 = *(const f32x4*)&aw[base + 4];                             \
        f32x4 a2 = *(const f32x4*)&aw[base + 8];                             \
        float aa[12] = { a0[0],a0[1],a0[2],a0[3],                            \
                         a1[0],a1[1],a1[2],a1[3],                            \
                         a2[0],a2[1],a2[2],a2[3] };                          \
        _Pragma("unroll")                                                    \
        for (int jj = 0; jj < 4; jj++) {                                     \
            _Pragma("unroll")                                                \
            for (int r = 0; r < 4; r++) {                                    \
                float qv = q4[r][jj];                                        \
                _Pragma("unroll")                                            \
                for (int ii = 0; ii < 8; ii++)                               \
                    acc[r][ii] = fmaf(aa[ii + 3 - jj], qv, acc[r][ii]);      \
            }                                                                \
        }                                                                    \
    }

// ---------------- K3: Toeplitz along W -> O (bf16) ------------------------
__global__ __launch_bounds__(256) void tno_w_kernel(
    const u16* __restrict__ QV, const float* __restrict__ Aco,
    u16* __restrict__ O)
{
    int bh0 = blockIdx.x * 4;       // four consecutive b*56+h rows
    int d0 = blockIdx.y * 32;
    TNO_STAGE4(QV[((bh0 + r) * 56 + jj) * D1 + d0 + d])
    if (i0 < 56) {
        #pragma unroll
        for (int r = 0; r < 4; r++)
            #pragma unroll
            for (int ii = 0; ii < 8; ii++)
                O[((bh0 + r) * 56 + (i0 + ii)) * D1 + d0 + d] = f2bf(acc[r][ii]);
    }
}

// ---------------- K4: Toeplitz along H, fuse U = P .* (o1 + o2) -----------
// bw0 = 4*blockIdx.x; since 56 % 4 == 0 all four rows share b.
__global__ __launch_bounds__(256) void tno_h_kernel(
    const u16* __restrict__ QV, const float* __restrict__ Aco,
    const u16* __restrict__ O, u16* __restrict__ PU)
{
    int bw0 = blockIdx.x * 4;
    int b = bw0 / 56, wb_ = bw0 % 56;
    int d0 = blockIdx.y * 32;
    TNO_STAGE4(QV[((b * 56 + jj) * 56 + (wb_ + r)) * D1 + d0 + d])
    if (i0 < 56) {
        #pragma unroll
        for (int r = 0; r < 4; r++)
            #pragma unroll
            for (int ii = 0; ii < 8; ii++) {
                int i = i0 + ii;
                int idx = ((b * 56 + i) * 56 + (wb_ + r)) * D1 + d0 + d;
                float o = bf2f(O[idx]) + acc[r][ii];
                float p = bf2f(PU[idx]);
                PU[idx] = f2bf(p * o);
            }
    }
}

// ---------------- K5: MFMA outproj: out = U @ ow^T + ob -------------------
__global__ __launch_bounds__(256) void outproj_kernel(
    const u16* __restrict__ U, const u16* __restrict__ owb,
    const float* __restrict__ ob, float* __restrict__ out)
{
    __shared__ char ldsraw[36864];
    u16* As = (u16*)ldsraw;
    u16* Bs = (u16*)(ldsraw + 16384);
    int m0 = blockIdx.x * 128, n0 = blockIdx.y * 64;
    int t = threadIdx.x;
    int l = t & 63, wave = t >> 6;
    int wm = wave >> 1, wn = wave & 1;
    int col16 = l & 15, q = l >> 4;

    f32x4 acc[4][2];
    #pragma unroll
    for (int i = 0; i < 4; i++)
        #pragma unroll
        for (int j = 0; j < 2; j++) acc[i][j] = (f32x4){0,0,0,0};

    for (int k0 = 0; k0 < D1; k0 += 64) {
        #pragma unroll
        for (int ii = 0; ii < 4; ii++) {
            int slot = (ii * 4 + wave) * 64 + l;
            int r = slot >> 3, s = slot & 7;
            int g = s ^ (r & 7);
            async16(&As[slot * 8], U + (m0 + r) * D1 + k0 + g * 8);
        }
        #pragma unroll
        for (int ii = 0; ii < 2; ii++) {
            int slot = (ii * 4 + wave) * 64 + l;
            int r = slot >> 3, s = slot & 7;
            int g = s ^ (r & 7);
            async16(&Bs[slot * 8], owb + (n0 + r) * D1 + k0 + g * 8);
        }
        __syncthreads();

        #pragma unroll
        for (int kk = 0; kk < 2; kk++) {
            int sw = (q + 4 * kk) ^ (col16 & 7);
            bf16x8 af[4];
            #pragma unroll
            for (int mt = 0; mt < 4; mt++)
                af[mt] = *(const bf16x8*)&As[(wm * 64 + mt * 16 + col16) * 64 + sw * 8];
            bf16x8 bfr[2];
            #pragma unroll
            for (int nt = 0; nt < 2; nt++)
                bfr[nt] = *(const bf16x8*)&Bs[(wn * 32 + nt * 16 + col16) * 64 + sw * 8];
            #pragma unroll
            for (int mt = 0; mt < 4; mt++)
                #pragma unroll
                for (int nt = 0; nt < 2; nt++)
                    acc[mt][nt] = __builtin_amdgcn_mfma_f32_16x16x32_bf16(
                        af[mt], bfr[nt], acc[mt][nt], 0, 0, 0);
        }
        __syncthreads();
    }

    float* scr = (float*)ldsraw + wave * 2304;
    float obv[2];
    #pragma unroll
    for (int nt = 0; nt < 2; nt++)
        obv[nt] = ob[n0 + wn * 32 + nt * 16 + col16];
    #pragma unroll
    for (int mt = 0; mt < 4; mt++)
        #pragma unroll
        for (int nt = 0; nt < 2; nt++)
            #pragma unroll
            for (int r = 0; r < 4; r++)
                scr[(mt * 16 + q * 4 + r) * 36 + nt * 16 + col16] =
                    acc[mt][nt][r] + obv[nt];
    #pragma unroll
    for (int k = 0; k < 8; k++) {
        int row = k * 8 + (l >> 3), cs = (l & 7) * 4;
        f32x4 v = *(const f32x4*)&scr[row * 36 + cs];
        *(f32x4*)&out[(m0 + wm * 64 + row) * EMB + n0 + wn * 32 + cs] = v;
    }
}

extern "C" void kernel_launch(void* const* d_in, const int* in_sizes, int n_in,
                              void* d_out, int out_size, void* d_ws, size_t ws_size,
                              hipStream_t stream)
{
    (void)in_sizes; (void)n_in; (void)out_size; (void)ws_size;
    const float* x     = (const float*)d_in[0];
    const float* p_w   = (const float*)d_in[1];
    const float* p_b   = (const float*)d_in[2];
    const float* q_w   = (const float*)d_in[3];
    const float* q_b   = (const float*)d_in[4];
    const float* v_w   = (const float*)d_in[5];
    const float* v_b   = (const float*)d_in[6];
    const float* o_w   = (const float*)d_in[7];
    const float* o_b   = (const float*)d_in[8];
    const float* slope = (const float*)d_in[9];
    const float* t1_w0 = (const float*)d_in[10];
    const float* t1_b0 = (const float*)d_in[11];
    const float* t1_ws = (const float*)d_in[12];
    const float* t1_bs = (const float*)d_in[13];
    const float* t1_wo = (const float*)d_in[14];
    const float* t1_bo = (const float*)d_in[15];
    const float* t2_w0 = (const float*)d_in[16];
    const float* t2_b0 = (const float*)d_in[17];
    const float* t2_ws = (const float*)d_in[18];
    const float* t2_bs = (const float*)d_in[19];
    const float* t2_wo = (const float*)d_in[20];
    const float* t2_bo = (const float*)d_in[21];

    char* ws = (char*)d_ws;
    float* A1 = (float*)ws;                      // 258048 B
    float* A2 = (float*)(ws + 258048);           // 258048 B
    u16*   PU = (u16*)(ws + 516096);             // 28901376 B (P, later U)
    u16*   QV = (u16*)(ws + 29417472);           // 28901376 B
    u16*   O  = (u16*)(ws + 58318848);           // 28901376 B (bf16)
    u16*   xb = (u16*)(ws + 87220224);           // 9633792 B
    u16*   wb = (u16*)(ws + 96854016);           // 663552 B
    u16*   owb= (u16*)(ws + 97517568);           // 221184 B

    convert_kernel<<<(XCH + 4*WCH + 255) / 256, 256, 0, stream>>>(
        x, p_w, q_w, v_w, o_w, xb, wb, owb);
    rpe_kernel<<<224, 576, 0, stream>>>(slope,
        t1_w0, t1_b0, t1_ws, t1_bs, t1_wo, t1_bo,
        t2_w0, t2_b0, t2_ws, t2_bs, t2_wo, t2_bo, A1, A2);
    proj_kernel<<<dim3(TOK / 128, D1 / 64), 256, 0, stream>>>(
        xb, wb, p_b, q_b, v_b, PU, QV);
    tno_w_kernel<<<dim3(NB * NN / 4, D1 / 32), 256, 0, stream>>>(QV, A1, O);
    tno_h_kernel<<<dim3(NB * NN / 4, D1 / 32), 256, 0, stream>>>(QV, A2, O, PU);
    outproj_kernel<<<dim3(TOK / 128, EMB / 64), 256, 0, stream>>>(
        PU, owb, o_b, (float*)d_out);
}